// Round 2
// baseline (131.968 us; speedup 1.0000x reference)
//
#include <hip/hip_runtime.h>
#include <math.h>

#define EPS 1e-9f

constexpr int Bn = 1024, Dn = 512, Un = 512;
constexpr int BM = 64;      // rows of B per block
constexpr int BU = 64;      // cols of U per block
constexpr int DK = 32;      // k-chunk staged in LDS
constexpr int SPLITD = 8;   // D split across blocks (atomicAdd combine) -> 1024 blocks = 4/CU
constexpr int DPB = Dn / SPLITD;    // 64 d per block
constexpr int NCHUNK = DPB / DK;    // 2 chunks

__global__ __launch_bounds__(256) void power_layer(
    const float* __restrict__ x, const float* __restrict__ w,
    const float* __restrict__ p, const float* __restrict__ bias,
    float* __restrict__ out)
{
    // d-major LDS layout: inner loop reads float4 over rows/cols,
    // per-d address step is a 256B immediate offset for ds_read_b128.
    __shared__ float sL[DK][BM];   // Lenc = sign(neg) * (log2|x+eps| + 64)
    __shared__ float sP[DK][BU];   // p
    __shared__ float sW[DK][BU];   // w
    __shared__ float sWX[DK][BU];  // odd(p) ? -w : w

    const int tid = threadIdx.x;
    const int tx = tid & 15;        // col group
    const int ty = tid >> 4;        // row group
    const int ub = blockIdx.x * BU;
    const int bb = blockIdx.y * BM;
    const int d0 = blockIdx.z * DPB;

    float acc[4][4] = {};

    for (int ch = 0; ch < NCHUNK; ++ch) {
        const int db = d0 + ch * DK;

        // ---- stage x tile -> sL (64 rows x 32 d), transposed to [d][row] ----
        {
            int t = tid;
            #pragma unroll
            for (int it = 0; it < 2; ++it, t += 256) {
                const int r  = t >> 3;            // 0..63
                const int dq = (t & 7) << 2;      // 0,4,...,28
                const float4 xv = *reinterpret_cast<const float4*>(
                    &x[(size_t)(bb + r) * Dn + db + dq]);
                const float* xs = reinterpret_cast<const float*>(&xv);
                #pragma unroll
                for (int j = 0; j < 4; ++j) {
                    const float xe = xs[j] + EPS;
                    const float La = __builtin_amdgcn_logf(fabsf(xe)) + 64.0f;
                    sL[dq + j][r] = (xe < 0.0f) ? -La : La;
                }
            }
        }
        // ---- stage p,w tiles (32 d x 64 u), natural layout, float4 writes ----
        {
            int t = tid;
            #pragma unroll
            for (int it = 0; it < 2; ++it, t += 256) {
                const int d  = t >> 4;            // 0..31
                const int uq = (t & 15) << 2;     // 0..60
                const size_t gi = (size_t)(db + d) * Un + ub + uq;
                const float4 pv = *reinterpret_cast<const float4*>(&p[gi]);
                const float4 wv = *reinterpret_cast<const float4*>(&w[gi]);
                const float* ps = reinterpret_cast<const float*>(&pv);
                const float* wsv = reinterpret_cast<const float*>(&wv);
                float4 wxv;
                float* wxs = reinterpret_cast<float*>(&wxv);
                #pragma unroll
                for (int j = 0; j < 4; ++j) {
                    const bool odd = (fmodf(ps[j], 2.0f) != 0.0f);
                    wxs[j] = odd ? -wsv[j] : wsv[j];
                }
                *reinterpret_cast<float4*>(&sP[d][uq])  = pv;
                *reinterpret_cast<float4*>(&sW[d][uq])  = wv;
                *reinterpret_cast<float4*>(&sWX[d][uq]) = wxv;
            }
        }
        __syncthreads();

        #pragma unroll 8
        for (int d = 0; d < DK; ++d) {
            const float4 Lv  = *reinterpret_cast<const float4*>(&sL[d][ty * 4]);
            const float4 Pv  = *reinterpret_cast<const float4*>(&sP[d][tx * 4]);
            const float4 Wv  = *reinterpret_cast<const float4*>(&sW[d][tx * 4]);
            const float4 WXv = *reinterpret_cast<const float4*>(&sWX[d][tx * 4]);
            const float* Ls  = reinterpret_cast<const float*>(&Lv);
            const float* Ps  = reinterpret_cast<const float*>(&Pv);
            const float* Ws  = reinterpret_cast<const float*>(&Wv);
            const float* WXs = reinterpret_cast<const float*>(&WXv);
            #pragma unroll
            for (int r = 0; r < 4; ++r) {
                const float Lenc = Ls[r];
                const float L    = fabsf(Lenc) - 64.0f;
                const bool  neg  = Lenc < 0.0f;
                #pragma unroll
                for (int c = 0; c < 4; ++c) {
                    const float tt  = Ps[c] * L;
                    const float e   = __builtin_amdgcn_exp2f(tt);
                    const float wgt = neg ? WXs[c] : Ws[c];
                    acc[r][c] = fmaf(wgt, e, acc[r][c]);
                }
            }
        }
        __syncthreads();
    }

    // bias folded into the z==0 slice (out was zeroed by memset)
    if (blockIdx.z == 0) {
        const float4 bv = *reinterpret_cast<const float4*>(&bias[ub + tx * 4]);
        const float* bs = reinterpret_cast<const float*>(&bv);
        #pragma unroll
        for (int r = 0; r < 4; ++r)
            #pragma unroll
            for (int c = 0; c < 4; ++c)
                acc[r][c] += bs[c];
    }

    // combine split-D partials
    #pragma unroll
    for (int r = 0; r < 4; ++r) {
        const int row = bb + ty * 4 + r;
        #pragma unroll
        for (int c = 0; c < 4; ++c) {
            atomicAdd(&out[(size_t)row * Un + ub + tx * 4 + c], acc[r][c]);
        }
    }
}

extern "C" void kernel_launch(void* const* d_in, const int* in_sizes, int n_in,
                              void* d_out, int out_size, void* d_ws, size_t ws_size,
                              hipStream_t stream) {
    const float* x = (const float*)d_in[0];
    const float* w = (const float*)d_in[1];
    const float* p = (const float*)d_in[2];
    const float* b = (const float*)d_in[3];
    float* out = (float*)d_out;

    // out = 0; bias is added by the blockIdx.z==0 slice
    hipMemsetAsync(out, 0, (size_t)out_size * sizeof(float), stream);

    power_layer<<<dim3(Un / BU, Bn / BM, SPLITD), dim3(256), 0, stream>>>(x, w, p, b, out);
}

// Round 3
// 113.630 us; speedup vs baseline: 1.1614x; 1.1614x over previous
//
#include <hip/hip_runtime.h>
#include <math.h>

#define EPS 1e-9f

constexpr int Bn = 1024, Dn = 512, Un = 512;
constexpr int BM = 64;      // rows of B per block
constexpr int BU = 64;      // cols of U per block
constexpr int DK = 32;      // k-chunk staged in LDS
constexpr int SPLITD = 8;   // D split across blocks -> 1024 blocks = 4/CU
constexpr int DPB = Dn / SPLITD;    // 64 d per block
constexpr int NCHUNK = DPB / DK;    // 2 chunks

// USE_WS=true : store per-z partials to ws (plain float4 stores, no atomics)
// USE_WS=false: atomicAdd into out (fallback when ws too small), bias folded at z==0
template <bool USE_WS>
__global__ __launch_bounds__(256, 4) void power_layer(
    const float* __restrict__ x, const float* __restrict__ w,
    const float* __restrict__ p, const float* __restrict__ bias,
    float* __restrict__ outp)
{
    __shared__ float sL[DK][BM];   // Lenc = sign(neg) * (log2|x+eps| + 64)
    __shared__ float sP[DK][BU];   // p
    __shared__ float sW[DK][BU];   // w
    __shared__ float sWX[DK][BU];  // odd(p) ? -w : w

    const int tid = threadIdx.x;
    const int tx  = tid & 15;
    const int ty  = tid >> 4;
    const int tx4 = tx * 4;
    const int ty4 = ty * 4;
    const int ub = blockIdx.x * BU;
    const int bb = blockIdx.y * BM;
    const int d0 = blockIdx.z * DPB;

    float acc[4][4] = {};

    for (int ch = 0; ch < NCHUNK; ++ch) {
        const int db = d0 + ch * DK;

        // ---- stage x tile -> sL (64 rows x 32 d), transposed to [d][row] ----
        {
            int t = tid;
            #pragma unroll
            for (int it = 0; it < 2; ++it, t += 256) {
                const int r  = t >> 3;            // 0..63
                const int dq = (t & 7) << 2;      // 0,4,...,28
                const float4 xv = *reinterpret_cast<const float4*>(
                    &x[(size_t)(bb + r) * Dn + db + dq]);
                const float* xs = reinterpret_cast<const float*>(&xv);
                #pragma unroll
                for (int j = 0; j < 4; ++j) {
                    const float xe = xs[j] + EPS;
                    const float La = __builtin_amdgcn_logf(fabsf(xe)) + 64.0f;
                    sL[dq + j][r] = (xe < 0.0f) ? -La : La;
                }
            }
        }
        // ---- stage p,w tiles (32 d x 64 u), natural layout, float4 writes ----
        {
            int t = tid;
            #pragma unroll
            for (int it = 0; it < 2; ++it, t += 256) {
                const int d  = t >> 4;            // 0..31
                const int uq = (t & 15) << 2;     // 0..60
                const size_t gi = (size_t)(db + d) * Un + ub + uq;
                const float4 pv = *reinterpret_cast<const float4*>(&p[gi]);
                const float4 wv = *reinterpret_cast<const float4*>(&w[gi]);
                const float* ps  = reinterpret_cast<const float*>(&pv);
                const float* wsv = reinterpret_cast<const float*>(&wv);
                float4 wxv;
                float* wxs = reinterpret_cast<float*>(&wxv);
                #pragma unroll
                for (int j = 0; j < 4; ++j) {
                    const bool odd = (fmodf(ps[j], 2.0f) != 0.0f);
                    wxs[j] = odd ? -wsv[j] : wsv[j];
                }
                *reinterpret_cast<float4*>(&sP[d][uq])  = pv;
                *reinterpret_cast<float4*>(&sW[d][uq])  = wv;
                *reinterpret_cast<float4*>(&sWX[d][uq]) = wxv;
            }
        }
        __syncthreads();

        // ---- software-pipelined inner loop: prefetch d+1 while computing d ----
        float4 Lv = *reinterpret_cast<const float4*>(&sL[0][ty4]);
        float4 Pv = *reinterpret_cast<const float4*>(&sP[0][tx4]);
        float4 Wv = *reinterpret_cast<const float4*>(&sW[0][tx4]);
        float4 Xv = *reinterpret_cast<const float4*>(&sWX[0][tx4]);

        #pragma unroll 4
        for (int d = 0; d < DK; ++d) {
            const int dn = (d + 1) & (DK - 1);   // wrap: last prefetch is discarded
            const float4 Ln = *reinterpret_cast<const float4*>(&sL[dn][ty4]);
            const float4 Pn = *reinterpret_cast<const float4*>(&sP[dn][tx4]);
            const float4 Wn = *reinterpret_cast<const float4*>(&sW[dn][tx4]);
            const float4 Xn = *reinterpret_cast<const float4*>(&sWX[dn][tx4]);

            const float* Ls = reinterpret_cast<const float*>(&Lv);
            const float* Ps = reinterpret_cast<const float*>(&Pv);
            const float* Ws = reinterpret_cast<const float*>(&Wv);
            const float* Xs = reinterpret_cast<const float*>(&Xv);

            float Ld[4];
            bool  ng[4];
            #pragma unroll
            for (int r = 0; r < 4; ++r) {
                Ld[r] = fabsf(Ls[r]) - 64.0f;
                ng[r] = Ls[r] < 0.0f;
            }

            // batch all 16 exps (independent) before any consumer
            float ev[16];
            #pragma unroll
            for (int r = 0; r < 4; ++r)
                #pragma unroll
                for (int c = 0; c < 4; ++c)
                    ev[r * 4 + c] = __builtin_amdgcn_exp2f(Ps[c] * Ld[r]);

            #pragma unroll
            for (int r = 0; r < 4; ++r)
                #pragma unroll
                for (int c = 0; c < 4; ++c)
                    acc[r][c] = fmaf(ng[r] ? Xs[c] : Ws[c], ev[r * 4 + c], acc[r][c]);

            Lv = Ln; Pv = Pn; Wv = Wn; Xv = Xn;
        }
        __syncthreads();
    }

    if (USE_WS) {
        // plain coalesced partial stores: ws[z][b][u]
        float* dst = outp + ((size_t)blockIdx.z * Bn + bb + ty4) * Un + ub + tx4;
        #pragma unroll
        for (int r = 0; r < 4; ++r) {
            float4 st = make_float4(acc[r][0], acc[r][1], acc[r][2], acc[r][3]);
            *reinterpret_cast<float4*>(dst + (size_t)r * Un) = st;
        }
    } else {
        if (blockIdx.z == 0) {
            const float4 bv = *reinterpret_cast<const float4*>(&bias[ub + tx4]);
            const float* bs = reinterpret_cast<const float*>(&bv);
            #pragma unroll
            for (int r = 0; r < 4; ++r)
                #pragma unroll
                for (int c = 0; c < 4; ++c)
                    acc[r][c] += bs[c];
        }
        #pragma unroll
        for (int r = 0; r < 4; ++r) {
            const int row = bb + ty4 + r;
            #pragma unroll
            for (int c = 0; c < 4; ++c)
                atomicAdd(&outp[(size_t)row * Un + ub + tx4 + c], acc[r][c]);
        }
    }
}

// out[b,u] = sum_z ws[z][b][u] + bias[u]   (float4 per thread)
__global__ __launch_bounds__(256) void reduce_ws(
    const float* __restrict__ ws, const float* __restrict__ bias,
    float* __restrict__ out)
{
    const int nf4 = (Bn * Un) / 4;   // 131072
    const int i = blockIdx.x * 256 + threadIdx.x;
    if (i >= nf4) return;
    const float4* w4 = reinterpret_cast<const float4*>(ws);
    float4 a = w4[i];
    #pragma unroll
    for (int z = 1; z < SPLITD; ++z) {
        const float4 t = w4[(size_t)z * nf4 + i];
        a.x += t.x; a.y += t.y; a.z += t.z; a.w += t.w;
    }
    const float4 bv = reinterpret_cast<const float4*>(bias)[i & (Un / 4 - 1)];
    a.x += bv.x; a.y += bv.y; a.z += bv.z; a.w += bv.w;
    reinterpret_cast<float4*>(out)[i] = a;
}

extern "C" void kernel_launch(void* const* d_in, const int* in_sizes, int n_in,
                              void* d_out, int out_size, void* d_ws, size_t ws_size,
                              hipStream_t stream) {
    const float* x = (const float*)d_in[0];
    const float* w = (const float*)d_in[1];
    const float* p = (const float*)d_in[2];
    const float* b = (const float*)d_in[3];
    float* out = (float*)d_out;

    const dim3 grid(Un / BU, Bn / BM, SPLITD);
    const size_t need = (size_t)SPLITD * Bn * Un * sizeof(float);   // 16 MB

    if (ws_size >= need) {
        float* wsf = (float*)d_ws;
        power_layer<true><<<grid, dim3(256), 0, stream>>>(x, w, p, b, wsf);
        reduce_ws<<<dim3((Bn * Un / 4 + 255) / 256), dim3(256), 0, stream>>>(wsf, b, out);
    } else {
        hipMemsetAsync(out, 0, (size_t)out_size * sizeof(float), stream);
        power_layer<false><<<grid, dim3(256), 0, stream>>>(x, w, p, b, out);
    }
}

// Round 4
// 111.319 us; speedup vs baseline: 1.1855x; 1.0208x over previous
//
#include <hip/hip_runtime.h>
#include <math.h>

#define EPS 1e-9f

constexpr int Bn = 1024, Dn = 512, Un = 512;
constexpr int BM = 64;      // rows of B per block
constexpr int BU = 64;      // cols of U per block
constexpr int DK = 32;      // k-chunk staged in LDS
constexpr int SPLITD = 8;   // D split across blocks -> 1024 blocks = 4/CU
constexpr int DPB = Dn / SPLITD;    // 64 d per block
constexpr int NCHUNK = DPB / DK;    // 2 chunks

// XOR swizzle for sL columns: kills the 8-way bank conflict on transposed
// staging writes (lane stride 256B -> all same bank). Bits 3-4 only, so
// 4-float alignment of b128 reads is preserved.
__device__ __forceinline__ int swz(int d) { return ((d >> 2) & 3) << 3; }

template <bool USE_WS>
__global__ __launch_bounds__(256, 4) void power_layer(
    const float* __restrict__ x, const float* __restrict__ w,
    const float* __restrict__ p, const float* __restrict__ bias,
    float* __restrict__ outp)
{
    __shared__ float sL[DK][BM];   // Lenc = sign(neg) * (log2|x+eps| + 64), swizzled cols
    __shared__ float sP[DK][BU];   // p
    __shared__ float sW[DK][BU];   // w
    __shared__ float sWX[DK][BU];  // odd(p) ? -w : w

    const int tid = threadIdx.x;
    const int tx  = tid & 15;
    const int ty  = tid >> 4;
    const int tx4 = tx * 4;
    const int ty4 = ty * 4;
    const int ub = blockIdx.x * BU;
    const int bb = blockIdx.y * BM;
    const int d0 = blockIdx.z * DPB;

    float acc[4][4] = {};

    for (int ch = 0; ch < NCHUNK; ++ch) {
        const int db = d0 + ch * DK;

        // ---- stage x tile -> sL (transposed, swizzled) ----
        {
            int t = tid;
            #pragma unroll
            for (int it = 0; it < 2; ++it, t += 256) {
                const int r  = t >> 3;            // 0..63
                const int dq = (t & 7) << 2;      // 0,4,...,28
                const float4 xv = *reinterpret_cast<const float4*>(
                    &x[(size_t)(bb + r) * Dn + db + dq]);
                const float* xs = reinterpret_cast<const float*>(&xv);
                #pragma unroll
                for (int j = 0; j < 4; ++j) {
                    const float xe = xs[j] + EPS;
                    const float La = __builtin_amdgcn_logf(fabsf(xe)) + 64.0f;
                    const int dd = dq + j;
                    sL[dd][r ^ swz(dd)] = (xe < 0.0f) ? -La : La;
                }
            }
        }
        // ---- stage p,w tiles (natural layout, float4, conflict-free) ----
        {
            int t = tid;
            #pragma unroll
            for (int it = 0; it < 2; ++it, t += 256) {
                const int d  = t >> 4;            // 0..31
                const int uq = (t & 15) << 2;     // 0..60
                const size_t gi = (size_t)(db + d) * Un + ub + uq;
                const float4 pv = *reinterpret_cast<const float4*>(&p[gi]);
                const float4 wv = *reinterpret_cast<const float4*>(&w[gi]);
                const float* ps  = reinterpret_cast<const float*>(&pv);
                const float* wsv = reinterpret_cast<const float*>(&wv);
                float4 wxv;
                float* wxs = reinterpret_cast<float*>(&wxv);
                #pragma unroll
                for (int j = 0; j < 4; ++j) {
                    const bool odd = (fmodf(ps[j], 2.0f) != 0.0f);
                    wxs[j] = odd ? -wsv[j] : wsv[j];
                }
                *reinterpret_cast<float4*>(&sP[d][uq])  = pv;
                *reinterpret_cast<float4*>(&sW[d][uq])  = wv;
                *reinterpret_cast<float4*>(&sWX[d][uq]) = wxv;
            }
        }
        __syncthreads();

        // ---- inner loop: 2 d's jammed, 32-exp batch per iteration ----
        #pragma unroll 4
        for (int d = 0; d < DK; d += 2) {
            float4 Lv[2], Pv[2], Wv[2], Xv[2];
            #pragma unroll
            for (int k = 0; k < 2; ++k) {
                Lv[k] = *reinterpret_cast<const float4*>(&sL[d + k][ty4 ^ swz(d + k)]);
                Pv[k] = *reinterpret_cast<const float4*>(&sP[d + k][tx4]);
                Wv[k] = *reinterpret_cast<const float4*>(&sW[d + k][tx4]);
                Xv[k] = *reinterpret_cast<const float4*>(&sWX[d + k][tx4]);
            }

            float Ld[2][4];
            bool  ng[2][4];
            #pragma unroll
            for (int k = 0; k < 2; ++k) {
                const float* Ls = reinterpret_cast<const float*>(&Lv[k]);
                #pragma unroll
                for (int r = 0; r < 4; ++r) {
                    Ld[k][r] = fabsf(Ls[r]) - 64.0f;
                    ng[k][r] = Ls[r] < 0.0f;
                }
            }

            // batch all 32 independent exps before any consumer
            float ev[2][16];
            #pragma unroll
            for (int k = 0; k < 2; ++k) {
                const float* Ps = reinterpret_cast<const float*>(&Pv[k]);
                #pragma unroll
                for (int r = 0; r < 4; ++r)
                    #pragma unroll
                    for (int c = 0; c < 4; ++c)
                        ev[k][r * 4 + c] = __builtin_amdgcn_exp2f(Ps[c] * Ld[k][r]);
            }

            #pragma unroll
            for (int k = 0; k < 2; ++k) {
                const float* Ws = reinterpret_cast<const float*>(&Wv[k]);
                const float* Xs = reinterpret_cast<const float*>(&Xv[k]);
                #pragma unroll
                for (int r = 0; r < 4; ++r)
                    #pragma unroll
                    for (int c = 0; c < 4; ++c)
                        acc[r][c] = fmaf(ng[k][r] ? Xs[c] : Ws[c],
                                         ev[k][r * 4 + c], acc[r][c]);
            }
        }
        __syncthreads();
    }

    if (USE_WS) {
        // plain coalesced partial stores: ws[z][b][u]
        float* dst = outp + ((size_t)blockIdx.z * Bn + bb + ty4) * Un + ub + tx4;
        #pragma unroll
        for (int r = 0; r < 4; ++r) {
            float4 st = make_float4(acc[r][0], acc[r][1], acc[r][2], acc[r][3]);
            *reinterpret_cast<float4*>(dst + (size_t)r * Un) = st;
        }
    } else {
        if (blockIdx.z == 0) {
            const float4 bv = *reinterpret_cast<const float4*>(&bias[ub + tx4]);
            const float* bs = reinterpret_cast<const float*>(&bv);
            #pragma unroll
            for (int r = 0; r < 4; ++r)
                #pragma unroll
                for (int c = 0; c < 4; ++c)
                    acc[r][c] += bs[c];
        }
        #pragma unroll
        for (int r = 0; r < 4; ++r) {
            const int row = bb + ty4 + r;
            #pragma unroll
            for (int c = 0; c < 4; ++c)
                atomicAdd(&outp[(size_t)row * Un + ub + tx4 + c], acc[r][c]);
        }
    }
}

// out[b,u] = sum_z ws[z][b][u] + bias[u]   (float4 per thread)
__global__ __launch_bounds__(256) void reduce_ws(
    const float* __restrict__ ws, const float* __restrict__ bias,
    float* __restrict__ out)
{
    const int nf4 = (Bn * Un) / 4;   // 131072
    const int i = blockIdx.x * 256 + threadIdx.x;
    if (i >= nf4) return;
    const float4* w4 = reinterpret_cast<const float4*>(ws);
    float4 a = w4[i];
    #pragma unroll
    for (int z = 1; z < SPLITD; ++z) {
        const float4 t = w4[(size_t)z * nf4 + i];
        a.x += t.x; a.y += t.y; a.z += t.z; a.w += t.w;
    }
    const float4 bv = reinterpret_cast<const float4*>(bias)[i & (Un / 4 - 1)];
    a.x += bv.x; a.y += bv.y; a.z += bv.z; a.w += bv.w;
    reinterpret_cast<float4*>(out)[i] = a;
}

extern "C" void kernel_launch(void* const* d_in, const int* in_sizes, int n_in,
                              void* d_out, int out_size, void* d_ws, size_t ws_size,
                              hipStream_t stream) {
    const float* x = (const float*)d_in[0];
    const float* w = (const float*)d_in[1];
    const float* p = (const float*)d_in[2];
    const float* b = (const float*)d_in[3];
    float* out = (float*)d_out;

    const dim3 grid(Un / BU, Bn / BM, SPLITD);
    const size_t need = (size_t)SPLITD * Bn * Un * sizeof(float);   // 16 MB

    if (ws_size >= need) {
        float* wsf = (float*)d_ws;
        power_layer<true><<<grid, dim3(256), 0, stream>>>(x, w, p, b, wsf);
        reduce_ws<<<dim3((Bn * Un / 4 + 255) / 256), dim3(256), 0, stream>>>(wsf, b, out);
    } else {
        hipMemsetAsync(out, 0, (size_t)out_size * sizeof(float), stream);
        power_layer<false><<<grid, dim3(256), 0, stream>>>(x, w, p, b, out);
    }
}

// Round 6
// 110.754 us; speedup vs baseline: 1.1915x; 1.0051x over previous
//
#include <hip/hip_runtime.h>
#include <math.h>

#define EPS 1e-9f

constexpr int Bn = 1024, Dn = 512, Un = 512;
constexpr int BM = 32;      // rows of B per block (32 -> 2048 blocks = 8/CU)
constexpr int BU = 64;      // cols of U per block
constexpr int DK = 16;      // k-chunk staged in LDS (14KB/block)
constexpr int SPLITD = 8;   // D split across blocks; 16MB ws (proven R3/R4 path)
constexpr int DPB = Dn / SPLITD;    // 64 d per block
constexpr int NCHUNK = DPB / DK;    // 4 chunks

// XOR swizzle for sL columns: breaks the same-bank pattern of transposed
// staging writes. Bits 3-4 only, preserves float2/float4 alignment.
__device__ __forceinline__ int swz(int d) { return ((d >> 2) & 3) << 3; }

template <bool USE_WS>
__global__ __launch_bounds__(256, 4) void power_layer(
    const float* __restrict__ x, const float* __restrict__ w,
    const float* __restrict__ p, const float* __restrict__ bias,
    float* __restrict__ outp)
{
    __shared__ float sL[DK][BM];   // Lenc = sign(neg)*(log2|x+eps|+64), swizzled cols
    __shared__ float sP[DK][BU];   // p
    __shared__ float sW[DK][BU];   // w
    __shared__ float sWX[DK][BU];  // odd(p) ? -w : w

    const int tid = threadIdx.x;
    const int tx  = tid & 15;
    const int ty  = tid >> 4;
    const int tx4 = tx * 4;
    const int ty2 = ty * 2;
    const int ub = blockIdx.x * BU;
    const int bb = blockIdx.y * BM;
    const int d0 = blockIdx.z * DPB;

    float acc[2][4] = {};

    for (int ch = 0; ch < NCHUNK; ++ch) {
        const int db = d0 + ch * DK;

        // ---- stage x tile -> sL (32 rows x 16 d, transposed+swizzled) ----
        // 128 float4 loads; threads 0..127 (wave-uniform branch).
        if (tid < 128) {
            const int r  = tid >> 2;          // 0..31
            const int dq = (tid & 3) << 2;    // 0,4,8,12
            const float4 xv = *reinterpret_cast<const float4*>(
                &x[(size_t)(bb + r) * Dn + db + dq]);
            const float* xs = reinterpret_cast<const float*>(&xv);
            #pragma unroll
            for (int j = 0; j < 4; ++j) {
                const float xe = xs[j] + EPS;
                const float La = __builtin_amdgcn_logf(fabsf(xe)) + 64.0f;
                const int dd = dq + j;
                sL[dd][r ^ swz(dd)] = (xe < 0.0f) ? -La : La;
            }
        }
        // ---- stage p,w tiles (16 d x 64 u, natural layout, 1 float4/thread) ----
        {
            const int d  = tid >> 4;          // 0..15
            const int uq = (tid & 15) << 2;   // 0..60
            const size_t gi = (size_t)(db + d) * Un + ub + uq;
            const float4 pv = *reinterpret_cast<const float4*>(&p[gi]);
            const float4 wv = *reinterpret_cast<const float4*>(&w[gi]);
            const float* ps  = reinterpret_cast<const float*>(&pv);
            const float* wsv = reinterpret_cast<const float*>(&wv);
            float4 wxv;
            float* wxs = reinterpret_cast<float*>(&wxv);
            #pragma unroll
            for (int j = 0; j < 4; ++j) {
                const bool odd = (fmodf(ps[j], 2.0f) != 0.0f);
                wxs[j] = odd ? -wsv[j] : wsv[j];
            }
            *reinterpret_cast<float4*>(&sP[d][uq])  = pv;
            *reinterpret_cast<float4*>(&sW[d][uq])  = wv;
            *reinterpret_cast<float4*>(&sWX[d][uq]) = wxv;
        }
        __syncthreads();

        // ---- inner loop: single d, 8-exp batch; 2 rows x 4 cols per thread ----
        #pragma unroll 4
        for (int d = 0; d < DK; ++d) {
            const float2 Lv = *reinterpret_cast<const float2*>(&sL[d][ty2 ^ swz(d)]);
            const float4 Pv = *reinterpret_cast<const float4*>(&sP[d][tx4]);
            const float4 Wv = *reinterpret_cast<const float4*>(&sW[d][tx4]);
            const float4 Xv = *reinterpret_cast<const float4*>(&sWX[d][tx4]);
            const float* Ls = reinterpret_cast<const float*>(&Lv);
            const float* Ps = reinterpret_cast<const float*>(&Pv);
            const float* Ws = reinterpret_cast<const float*>(&Wv);
            const float* Xs = reinterpret_cast<const float*>(&Xv);

            float Ld[2];
            bool  ng[2];
            #pragma unroll
            for (int r = 0; r < 2; ++r) {
                Ld[r] = fabsf(Ls[r]) - 64.0f;
                ng[r] = Ls[r] < 0.0f;
            }

            // batch all 8 independent exps before any consumer
            float ev[8];
            #pragma unroll
            for (int r = 0; r < 2; ++r)
                #pragma unroll
                for (int c = 0; c < 4; ++c)
                    ev[r * 4 + c] = __builtin_amdgcn_exp2f(Ps[c] * Ld[r]);

            #pragma unroll
            for (int r = 0; r < 2; ++r)
                #pragma unroll
                for (int c = 0; c < 4; ++c)
                    acc[r][c] = fmaf(ng[r] ? Xs[c] : Ws[c], ev[r * 4 + c], acc[r][c]);
        }
        __syncthreads();
    }

    if (USE_WS) {
        // plain coalesced partial stores: ws[z][b][u]
        float* dst = outp + ((size_t)blockIdx.z * Bn + bb + ty2) * Un + ub + tx4;
        #pragma unroll
        for (int r = 0; r < 2; ++r) {
            float4 st = make_float4(acc[r][0], acc[r][1], acc[r][2], acc[r][3]);
            *reinterpret_cast<float4*>(dst + (size_t)r * Un) = st;
        }
    } else {
        if (blockIdx.z == 0) {
            const float4 bv = *reinterpret_cast<const float4*>(&bias[ub + tx4]);
            const float* bs = reinterpret_cast<const float*>(&bv);
            #pragma unroll
            for (int r = 0; r < 2; ++r)
                #pragma unroll
                for (int c = 0; c < 4; ++c)
                    acc[r][c] += bs[c];
        }
        #pragma unroll
        for (int r = 0; r < 2; ++r) {
            const int row = bb + ty2 + r;
            #pragma unroll
            for (int c = 0; c < 4; ++c)
                atomicAdd(&outp[(size_t)row * Un + ub + tx4 + c], acc[r][c]);
        }
    }
}

// out[b,u] = sum_z ws[z][b][u] + bias[u]   (float4 per thread)
__global__ __launch_bounds__(256) void reduce_ws(
    const float* __restrict__ ws, const float* __restrict__ bias,
    float* __restrict__ out)
{
    const int nf4 = (Bn * Un) / 4;   // 131072
    const int i = blockIdx.x * 256 + threadIdx.x;
    if (i >= nf4) return;
    const float4* w4 = reinterpret_cast<const float4*>(ws);
    float4 a = w4[i];
    #pragma unroll
    for (int z = 1; z < SPLITD; ++z) {
        const float4 t = w4[(size_t)z * nf4 + i];
        a.x += t.x; a.y += t.y; a.z += t.z; a.w += t.w;
    }
    const float4 bv = reinterpret_cast<const float4*>(bias)[i & (Un / 4 - 1)];
    a.x += bv.x; a.y += bv.y; a.z += bv.z; a.w += bv.w;
    reinterpret_cast<float4*>(out)[i] = a;
}

extern "C" void kernel_launch(void* const* d_in, const int* in_sizes, int n_in,
                              void* d_out, int out_size, void* d_ws, size_t ws_size,
                              hipStream_t stream) {
    const float* x = (const float*)d_in[0];
    const float* w = (const float*)d_in[1];
    const float* p = (const float*)d_in[2];
    const float* b = (const float*)d_in[3];
    float* out = (float*)d_out;

    const dim3 grid(Un / BU, Bn / BM, SPLITD);   // 8 x 32 x 8 = 2048 blocks
    const size_t need = (size_t)SPLITD * Bn * Un * sizeof(float);   // 16 MB

    if (ws_size >= need) {
        float* wsf = (float*)d_ws;
        power_layer<true><<<grid, dim3(256), 0, stream>>>(x, w, p, b, wsf);
        reduce_ws<<<dim3((Bn * Un / 4 + 255) / 256), dim3(256), 0, stream>>>(wsf, b, out);
    } else {
        hipMemsetAsync(out, 0, (size_t)out_size * sizeof(float), stream);
        power_layer<false><<<grid, dim3(256), 0, stream>>>(x, w, p, b, out);
    }
}

// Round 7
// 108.454 us; speedup vs baseline: 1.2168x; 1.0212x over previous
//
#include <hip/hip_runtime.h>
#include <math.h>

#define EPS 1e-9f

constexpr int Bn = 1024, Dn = 512, Un = 512;
constexpr int BM = 32;      // rows of B per block (2048 blocks = 8/CU)
constexpr int BU = 64;      // cols of U per block
constexpr int DK = 16;      // k-chunk staged in LDS (14KB/block)
constexpr int SPLITD = 8;   // D split across blocks; 16MB ws (proven path)
constexpr int DPB = Dn / SPLITD;    // 64 d per block
constexpr int NCHUNK = DPB / DK;    // 4 chunks

typedef float v4f __attribute__((ext_vector_type(4)));

// XOR swizzle for sL columns: breaks the same-bank pattern of transposed
// staging writes. Bits 3-4 only, preserves float2 alignment of reads.
__device__ __forceinline__ int swz(int d) { return ((d >> 2) & 3) << 3; }

template <bool USE_WS>
__global__ __launch_bounds__(256, 4) void power_layer(
    const float* __restrict__ x, const float* __restrict__ w,
    const float* __restrict__ p, const float* __restrict__ bias,
    float* __restrict__ outp)
{
    __shared__ float sL[DK][BM];   // Lenc = sign(neg)*(log2|x+eps|+64), swizzled cols
    __shared__ float sP[DK][BU];   // p
    __shared__ float sW[DK][BU];   // w
    __shared__ float sWX[DK][BU];  // odd(p) ? -w : w

    const int tid = threadIdx.x;
    const int tx  = tid & 15;
    const int ty  = tid >> 4;
    const int tx4 = tx * 4;
    const int ty2 = ty * 2;
    const int ub = blockIdx.x * BU;
    const int bb = blockIdx.y * BM;
    const int d0 = blockIdx.z * DPB;

    v4f acc[2] = {};   // 2 rows x 4 cols per thread, vector ops -> v_pk_*

    for (int ch = 0; ch < NCHUNK; ++ch) {
        const int db = d0 + ch * DK;

        // ---- stage x tile -> sL (32 rows x 16 d, transposed+swizzled) ----
        if (tid < 128) {
            const int r  = tid >> 2;          // 0..31
            const int dq = (tid & 3) << 2;    // 0,4,8,12
            const float4 xv = *reinterpret_cast<const float4*>(
                &x[(size_t)(bb + r) * Dn + db + dq]);
            const float* xs = reinterpret_cast<const float*>(&xv);
            #pragma unroll
            for (int j = 0; j < 4; ++j) {
                const float xe = xs[j] + EPS;
                const float La = __builtin_amdgcn_logf(fabsf(xe)) + 64.0f;
                const int dd = dq + j;
                sL[dd][r ^ swz(dd)] = (xe < 0.0f) ? -La : La;
            }
        }
        // ---- stage p,w tiles (16 d x 64 u, natural layout, 1 float4/thread) ----
        {
            const int d  = tid >> 4;          // 0..15
            const int uq = (tid & 15) << 2;   // 0..60
            const size_t gi = (size_t)(db + d) * Un + ub + uq;
            const float4 pv = *reinterpret_cast<const float4*>(&p[gi]);
            const float4 wv = *reinterpret_cast<const float4*>(&w[gi]);
            const float* ps  = reinterpret_cast<const float*>(&pv);
            const float* wsv = reinterpret_cast<const float*>(&wv);
            float4 wxv;
            float* wxs = reinterpret_cast<float*>(&wxv);
            #pragma unroll
            for (int j = 0; j < 4; ++j) {
                const bool odd = (fmodf(ps[j], 2.0f) != 0.0f);
                wxs[j] = odd ? -wsv[j] : wsv[j];
            }
            *reinterpret_cast<float4*>(&sP[d][uq])  = pv;
            *reinterpret_cast<float4*>(&sW[d][uq])  = wv;
            *reinterpret_cast<float4*>(&sWX[d][uq]) = wxv;
        }
        __syncthreads();

        // ---- inner loop: per d, per-row ADDRESS-selected weight fragment ----
        // (one pointer cndmask + ds_read_b128 per row replaces 4 value
        //  cndmasks; sW/sWX are 4KB apart -> identical bank mapping, no new
        //  conflicts). mul/fma on v4f -> v_pk_mul_f32 / v_pk_fma_f32.
        #pragma unroll 4
        for (int d = 0; d < DK; ++d) {
            const float2 Lv = *reinterpret_cast<const float2*>(&sL[d][ty2 ^ swz(d)]);
            const v4f    Pv = *reinterpret_cast<const v4f*>(&sP[d][tx4]);
            const float* Ls = reinterpret_cast<const float*>(&Lv);

            #pragma unroll
            for (int r = 0; r < 2; ++r) {
                const float Ld = fabsf(Ls[r]) - 64.0f;
                const bool  ng = Ls[r] < 0.0f;
                const v4f Wsel = *reinterpret_cast<const v4f*>(
                    ng ? &sWX[d][tx4] : &sW[d][tx4]);

                const v4f t = Pv * Ld;            // v_pk_mul_f32 x2
                v4f e;
                #pragma unroll
                for (int c = 0; c < 4; ++c)
                    e[c] = __builtin_amdgcn_exp2f(t[c]);
                acc[r] = __builtin_elementwise_fma(Wsel, e, acc[r]);  // v_pk_fma_f32 x2
            }
        }
        __syncthreads();
    }

    if (USE_WS) {
        // plain coalesced partial stores: ws[z][b][u]
        float* dst = outp + ((size_t)blockIdx.z * Bn + bb + ty2) * Un + ub + tx4;
        #pragma unroll
        for (int r = 0; r < 2; ++r)
            *reinterpret_cast<v4f*>(dst + (size_t)r * Un) = acc[r];
    } else {
        if (blockIdx.z == 0) {
            const v4f bv = *reinterpret_cast<const v4f*>(&bias[ub + tx4]);
            #pragma unroll
            for (int r = 0; r < 2; ++r)
                acc[r] += bv;
        }
        #pragma unroll
        for (int r = 0; r < 2; ++r) {
            const int row = bb + ty2 + r;
            #pragma unroll
            for (int c = 0; c < 4; ++c)
                atomicAdd(&outp[(size_t)row * Un + ub + tx4 + c], acc[r][c]);
        }
    }
}

// out[b,u] = sum_z ws[z][b][u] + bias[u]   (float4 per thread)
__global__ __launch_bounds__(256) void reduce_ws(
    const float* __restrict__ ws, const float* __restrict__ bias,
    float* __restrict__ out)
{
    const int nf4 = (Bn * Un) / 4;   // 131072
    const int i = blockIdx.x * 256 + threadIdx.x;
    if (i >= nf4) return;
    const v4f* w4 = reinterpret_cast<const v4f*>(ws);
    v4f a = w4[i];
    #pragma unroll
    for (int z = 1; z < SPLITD; ++z)
        a += w4[(size_t)z * nf4 + i];
    a += reinterpret_cast<const v4f*>(bias)[i & (Un / 4 - 1)];
    reinterpret_cast<v4f*>(out)[i] = a;
}

extern "C" void kernel_launch(void* const* d_in, const int* in_sizes, int n_in,
                              void* d_out, int out_size, void* d_ws, size_t ws_size,
                              hipStream_t stream) {
    const float* x = (const float*)d_in[0];
    const float* w = (const float*)d_in[1];
    const float* p = (const float*)d_in[2];
    const float* b = (const float*)d_in[3];
    float* out = (float*)d_out;

    const dim3 grid(Un / BU, Bn / BM, SPLITD);   // 8 x 32 x 8 = 2048 blocks
    const size_t need = (size_t)SPLITD * Bn * Un * sizeof(float);   // 16 MB

    if (ws_size >= need) {
        float* wsf = (float*)d_ws;
        power_layer<true><<<grid, dim3(256), 0, stream>>>(x, w, p, b, wsf);
        reduce_ws<<<dim3((Bn * Un / 4 + 255) / 256), dim3(256), 0, stream>>>(wsf, b, out);
    } else {
        hipMemsetAsync(out, 0, (size_t)out_size * sizeof(float), stream);
        power_layer<false><<<grid, dim3(256), 0, stream>>>(x, w, p, b, out);
    }
}